// Round 3
// baseline (665.407 us; speedup 1.0000x reference)
//
#include <hip/hip_runtime.h>

// ---------------------------------------------------------------------------
// AtomExposureGNN: 3-layer GCN (N=50000, E=800000, DIN=64, H=128) + MLP head
// Strategy: build CSR-by-dst on device each call (histogram + 2-level scan +
// atomic cursor), then per-node wave-parallel gather aggregation fused with
// bias+BN+ReLU+residual. GEMMs are fp32 register-tiled (no fp32 MFMA on CDNA4).
// ---------------------------------------------------------------------------

__device__ __forceinline__ void fma4(float4& acc, float s, const float4& v) {
    acc.x = fmaf(s, v.x, acc.x);
    acc.y = fmaf(s, v.y, acc.y);
    acc.z = fmaf(s, v.z, acc.z);
    acc.w = fmaf(s, v.w, acc.w);
}

constexpr int DIN_C = 64;
constexpr int H_C = 128;

// ---------------- CSR construction ----------------

__global__ __launch_bounds__(256) void count_deg_kernel(const int* __restrict__ dst,
                                                        int* __restrict__ cnt, int e) {
    int i = blockIdx.x * 256 + threadIdx.x;
    if (i < e) atomicAdd(&cnt[dst[i]], 1);
}

__global__ __launch_bounds__(512) void scan_blocks_kernel(const int* __restrict__ cnt,
                                                          int* __restrict__ excl,
                                                          int* __restrict__ bsums, int n) {
    __shared__ int s[2][512];
    int t = threadIdx.x;
    int i = blockIdx.x * 512 + t;
    int v = (i < n) ? cnt[i] : 0;
    s[0][t] = v;
    __syncthreads();
    int cur = 0;
    for (int off = 1; off < 512; off <<= 1) {
        int x = s[cur][t];
        if (t >= off) x += s[cur][t - off];
        s[cur ^ 1][t] = x;
        cur ^= 1;
        __syncthreads();
    }
    if (i < n) excl[i] = s[cur][t] - v;          // block-local exclusive
    if (t == 511) bsums[blockIdx.x] = s[cur][t]; // block total
}

__global__ __launch_bounds__(128) void scan_tops_kernel(const int* __restrict__ bsums,
                                                        int* __restrict__ btops, int nb) {
    __shared__ int s[2][128];
    int t = threadIdx.x;
    int v = (t < nb) ? bsums[t] : 0;
    s[0][t] = v;
    __syncthreads();
    int cur = 0;
    for (int off = 1; off < 128; off <<= 1) {
        int x = s[cur][t];
        if (t >= off) x += s[cur][t - off];
        s[cur ^ 1][t] = x;
        cur ^= 1;
        __syncthreads();
    }
    if (t < nb) btops[t] = s[cur][t] - v;        // exclusive over block sums
}

__global__ __launch_bounds__(512) void finalize_nodes_kernel(
        const int* __restrict__ excl, const int* __restrict__ btops,
        const int* __restrict__ cnt, int* __restrict__ row_ptr,
        int* __restrict__ cursor, float* __restrict__ dis, int n, int e) {
    int i = blockIdx.x * 512 + threadIdx.x;
    if (i < n) {
        int rp = excl[i] + btops[blockIdx.x];
        row_ptr[i] = rp;
        cursor[i]  = rp;
        // deg = edge indegree + 1 (self loop); always >= 1
        dis[i] = rsqrtf((float)(cnt[i] + 1));
    }
    if (i == 0) row_ptr[n] = e;
}

__global__ __launch_bounds__(256) void fill_csr_kernel(
        const int* __restrict__ src, const int* __restrict__ dst,
        int* __restrict__ cursor, const float* __restrict__ dis,
        int* __restrict__ csr_src, float* __restrict__ csr_norm, int e) {
    int i = blockIdx.x * 256 + threadIdx.x;
    if (i < e) {
        int s = src[i], d = dst[i];
        int pos = atomicAdd(&cursor[d], 1);
        csr_src[pos]  = s;
        csr_norm[pos] = dis[s] * dis[d];
    }
}

// ---------------- GEMM: C[M x NC] = act(A[M x K] @ W[K x NC] + bias) ----------------
// Register-tiled: thread = 8 rows x 4 cols. A reads are lane-broadcast (L1),
// W reads are coalesced float4 (L2-resident, <=64KB). VALU-bound by design.

template <int K, int NC, bool RELU, bool BIAS>
__global__ __launch_bounds__(256) void gemm_kernel(
        const float* __restrict__ A, const float* __restrict__ W,
        const float* __restrict__ bias, float* __restrict__ C, int M) {
    constexpr int CG  = NC / 4;      // col groups per row
    constexpr int RG  = 256 / CG;    // row-group threads
    constexpr int RPB = RG * 8;      // rows per block
    const int t  = threadIdx.x;
    const int tx = t % CG;
    const int ty = t / CG;
    const int c  = tx * 4;
    const int r0 = blockIdx.x * RPB + ty * 8;

    float4 bv = {0.f, 0.f, 0.f, 0.f};
    if (BIAS) bv = *(const float4*)&bias[c];

    if (r0 + 8 <= M) {
        float4 acc[8];
#pragma unroll
        for (int i = 0; i < 8; ++i) acc[i] = bv;
        const float* Ar = A + (size_t)r0 * K;
#pragma unroll 2
        for (int k0 = 0; k0 < K; k0 += 4) {
            float4 w0 = *(const float4*)&W[(size_t)(k0 + 0) * NC + c];
            float4 w1 = *(const float4*)&W[(size_t)(k0 + 1) * NC + c];
            float4 w2 = *(const float4*)&W[(size_t)(k0 + 2) * NC + c];
            float4 w3 = *(const float4*)&W[(size_t)(k0 + 3) * NC + c];
#pragma unroll
            for (int i = 0; i < 8; ++i) {
                float4 a = *(const float4*)&Ar[(size_t)i * K + k0];
                fma4(acc[i], a.x, w0);
                fma4(acc[i], a.y, w1);
                fma4(acc[i], a.z, w2);
                fma4(acc[i], a.w, w3);
            }
        }
        float* Cr = C + (size_t)r0 * NC + c;
#pragma unroll
        for (int i = 0; i < 8; ++i) {
            float4 v = acc[i];
            if (RELU) {
                v.x = fmaxf(v.x, 0.f); v.y = fmaxf(v.y, 0.f);
                v.z = fmaxf(v.z, 0.f); v.w = fmaxf(v.w, 0.f);
            }
            *(float4*)&Cr[(size_t)i * NC] = v;
        }
    } else {
        for (int i = 0; i < 8; ++i) {
            int r = r0 + i;
            if (r >= M) break;
            float4 acc = bv;
            const float* Ar = A + (size_t)r * K;
            for (int k0 = 0; k0 < K; k0 += 4) {
                float4 a  = *(const float4*)&Ar[k0];
                float4 w0 = *(const float4*)&W[(size_t)(k0 + 0) * NC + c];
                float4 w1 = *(const float4*)&W[(size_t)(k0 + 1) * NC + c];
                float4 w2 = *(const float4*)&W[(size_t)(k0 + 2) * NC + c];
                float4 w3 = *(const float4*)&W[(size_t)(k0 + 3) * NC + c];
                fma4(acc, a.x, w0);
                fma4(acc, a.y, w1);
                fma4(acc, a.z, w2);
                fma4(acc, a.w, w3);
            }
            if (RELU) {
                acc.x = fmaxf(acc.x, 0.f); acc.y = fmaxf(acc.y, 0.f);
                acc.z = fmaxf(acc.z, 0.f); acc.w = fmaxf(acc.w, 0.f);
            }
            *(float4*)&C[(size_t)r * NC + c] = acc;
        }
    }
}

// ---------------- Aggregation + bias + BN + ReLU + residual ----------------
// One 64-lane wave per node; lane covers features {lane, lane+64}.
// Gather hw[src] rows (coalesced 256B x2) scaled by precomputed edge norm.

__global__ __launch_bounds__(256) void agg_bn_kernel(
        const float* __restrict__ hw, const int* __restrict__ row_ptr,
        const int* __restrict__ csr_src, const float* __restrict__ csr_norm,
        const float* __restrict__ dis,
        const float* __restrict__ bc, const float* __restrict__ gamma_,
        const float* __restrict__ beta_, const float* __restrict__ rmean,
        const float* __restrict__ rvar,
        const float* __restrict__ h_in, float* __restrict__ h_out,
        int n, int residual) {
    int wid  = (blockIdx.x * 256 + threadIdx.x) >> 6;  // node id
    int lane = threadIdx.x & 63;
    if (wid >= n) return;

    const int f0 = lane, f1 = lane + 64;
    float d  = dis[wid];
    float sl = d * d;  // self-loop norm = 1/deg
    float acc0 = hw[(size_t)wid * H_C + f0] * sl;
    float acc1 = hw[(size_t)wid * H_C + f1] * sl;

    int beg = row_ptr[wid], end = row_ptr[wid + 1];
    for (int e = beg; e < end; ++e) {
        int   s   = csr_src[e];     // wave-uniform
        float nrm = csr_norm[e];    // wave-uniform
        const float* row = hw + (size_t)s * H_C;
        acc0 = fmaf(row[f0], nrm, acc0);
        acc1 = fmaf(row[f1], nrm, acc1);
    }

    const float eps = 1e-5f;
    float a0 = acc0 + bc[f0];
    float a1 = acc1 + bc[f1];
    float o0 = fmaf((a0 - rmean[f0]) * rsqrtf(rvar[f0] + eps), gamma_[f0], beta_[f0]);
    float o1 = fmaf((a1 - rmean[f1]) * rsqrtf(rvar[f1] + eps), gamma_[f1], beta_[f1]);
    o0 = fmaxf(o0, 0.f);
    o1 = fmaxf(o1, 0.f);
    if (residual) {
        o0 += h_in[(size_t)wid * H_C + f0];
        o1 += h_in[(size_t)wid * H_C + f1];
    }
    h_out[(size_t)wid * H_C + f0] = o0;
    h_out[(size_t)wid * H_C + f1] = o1;
}

// ---------------- Final dot: out[i] = t[i,:] . W2 + b2 ----------------

__global__ __launch_bounds__(256) void final_dot_kernel(
        const float* __restrict__ t, const float* __restrict__ W2,
        const float* __restrict__ b2, float* __restrict__ out, int n) {
    int wid  = (blockIdx.x * 256 + threadIdx.x) >> 6;
    int lane = threadIdx.x & 63;
    if (wid >= n) return;
    float v = t[(size_t)wid * 64 + lane] * W2[lane];
#pragma unroll
    for (int off = 32; off > 0; off >>= 1) v += __shfl_down(v, off, 64);
    if (lane == 0) out[wid] = v + b2[0];
}

// ---------------------------------------------------------------------------

extern "C" void kernel_launch(void* const* d_in, const int* in_sizes, int n_in,
                              void* d_out, int out_size, void* d_ws, size_t ws_size,
                              hipStream_t stream) {
    const float* x      = (const float*)d_in[0];
    const int*   ei     = (const int*)  d_in[1];
    const float* W_in   = (const float*)d_in[2];
    const float* b_in   = (const float*)d_in[3];
    const float* Wc     = (const float*)d_in[4];
    const float* bc     = (const float*)d_in[5];
    const float* gamma_ = (const float*)d_in[6];
    const float* beta_  = (const float*)d_in[7];
    const float* rmean  = (const float*)d_in[8];
    const float* rvar   = (const float*)d_in[9];
    const float* W1     = (const float*)d_in[10];
    const float* b1     = (const float*)d_in[11];
    const float* W2     = (const float*)d_in[12];
    const float* b2     = (const float*)d_in[13];
    float* out = (float*)d_out;

    const int M = in_sizes[0] / DIN_C;   // 50000 nodes
    const int E = in_sizes[1] / 2;       // 800000 edges
    const int* src = ei;
    const int* dst = ei + E;

    // Workspace carve-up (256B aligned)
    size_t off = 0;
    auto alloc = [&](size_t bytes) {
        void* p = (char*)d_ws + off;
        off += (bytes + 255) & ~(size_t)255;
        return p;
    };
    int*   cnt      = (int*)  alloc((size_t)M * 4);
    int*   excl     = (int*)  alloc((size_t)M * 4);
    int*   bsums    = (int*)  alloc(512);
    int*   btops    = (int*)  alloc(512);
    int*   row_ptr  = (int*)  alloc((size_t)(M + 1) * 4);
    int*   cursor   = (int*)  alloc((size_t)M * 4);
    float* dis      = (float*)alloc((size_t)M * 4);
    int*   csr_src  = (int*)  alloc((size_t)E * 4);
    float* csr_norm = (float*)alloc((size_t)E * 4);
    float* hA       = (float*)alloc((size_t)M * H_C * 4);
    float* hB       = (float*)alloc((size_t)M * H_C * 4);
    float* hw       = (float*)alloc((size_t)M * H_C * 4);
    float* t_buf    = hw;  // reuse hw for the MLP hidden (dead by then)

    const int NB = (M + 511) / 512;  // scan blocks (98 for M=50000, <=128)

    // ---- CSR build ----
    hipMemsetAsync(cnt, 0, (size_t)M * 4, stream);
    count_deg_kernel<<<(E + 255) / 256, 256, 0, stream>>>(dst, cnt, E);
    scan_blocks_kernel<<<NB, 512, 0, stream>>>(cnt, excl, bsums, M);
    scan_tops_kernel<<<1, 128, 0, stream>>>(bsums, btops, NB);
    finalize_nodes_kernel<<<NB, 512, 0, stream>>>(excl, btops, cnt, row_ptr, cursor, dis, M, E);
    fill_csr_kernel<<<(E + 255) / 256, 256, 0, stream>>>(src, dst, cursor, dis, csr_src, csr_norm, E);

    // ---- h0 = relu(x @ W_in + b_in) ----
    {
        constexpr int RPB = (256 / (H_C / 4)) * 8;  // 64 rows/block
        gemm_kernel<DIN_C, H_C, true, true><<<(M + RPB - 1) / RPB, 256, 0, stream>>>(
            x, W_in, b_in, hA, M);
    }

    // ---- 3 GCN layers ----
    float* cur = hA;
    float* nxt = hB;
    for (int layer = 0; layer < 3; ++layer) {
        constexpr int RPB = (256 / (H_C / 4)) * 8;
        gemm_kernel<H_C, H_C, false, false><<<(M + RPB - 1) / RPB, 256, 0, stream>>>(
            cur, Wc + (size_t)layer * H_C * H_C, nullptr, hw, M);
        agg_bn_kernel<<<(M * 64 + 255) / 256, 256, 0, stream>>>(
            hw, row_ptr, csr_src, csr_norm, dis,
            bc + (size_t)layer * H_C, gamma_ + (size_t)layer * H_C,
            beta_ + (size_t)layer * H_C, rmean + (size_t)layer * H_C,
            rvar + (size_t)layer * H_C,
            cur, nxt, M, layer > 0 ? 1 : 0);
        float* tmp = cur; cur = nxt; nxt = tmp;
    }

    // ---- head: out = relu(h @ W1 + b1) @ W2 + b2 ----
    {
        constexpr int RPB = (256 / (64 / 4)) * 8;  // 128 rows/block
        gemm_kernel<H_C, 64, true, true><<<(M + RPB - 1) / RPB, 256, 0, stream>>>(
            cur, W1, b1, t_buf, M);
    }
    final_dot_kernel<<<(M * 64 + 255) / 256, 256, 0, stream>>>(t_buf, W2, b2, out, M);
}

// Round 5
// 583.919 us; speedup vs baseline: 1.1396x; 1.1396x over previous
//
#include <hip/hip_runtime.h>

// ---------------------------------------------------------------------------
// AtomExposureGNN: 3-layer GCN (N=50000, E=800000, DIN=64, H=128) + MLP head
// R3 changes vs baseline (agg latency-bound, VALUBusy 15%, 2.57TB/s):
//  * agg gather: float4 lanes (32 lanes = full 512B row), 2 half-waves on
//    alternate edges + 2x unroll -> 4 independent loads in flight (was a
//    serial 2-load chain); cross-half combine via __shfl_xor(,32).
//  * separable norm dis[src]*dis[dst] folded: GEMM epilogue scales row r by
//    dis[r]; csr_norm array eliminated (less gather traffic + half the
//    scattered writes in fill_csr); agg epilogue multiplies by dis[dst].
// ---------------------------------------------------------------------------

__device__ __forceinline__ void fma4(float4& acc, float s, const float4& v) {
    acc.x = fmaf(s, v.x, acc.x);
    acc.y = fmaf(s, v.y, acc.y);
    acc.z = fmaf(s, v.z, acc.z);
    acc.w = fmaf(s, v.w, acc.w);
}
__device__ __forceinline__ void add4(float4& acc, const float4& v) {
    acc.x += v.x; acc.y += v.y; acc.z += v.z; acc.w += v.w;
}

constexpr int DIN_C = 64;
constexpr int H_C = 128;

// ---------------- CSR construction ----------------

__global__ __launch_bounds__(256) void count_deg_kernel(const int* __restrict__ dst,
                                                        int* __restrict__ cnt, int e) {
    int i = blockIdx.x * 256 + threadIdx.x;
    if (i < e) atomicAdd(&cnt[dst[i]], 1);
}

__global__ __launch_bounds__(512) void scan_blocks_kernel(const int* __restrict__ cnt,
                                                          int* __restrict__ excl,
                                                          int* __restrict__ bsums, int n) {
    __shared__ int s[2][512];
    int t = threadIdx.x;
    int i = blockIdx.x * 512 + t;
    int v = (i < n) ? cnt[i] : 0;
    s[0][t] = v;
    __syncthreads();
    int cur = 0;
    for (int off = 1; off < 512; off <<= 1) {
        int x = s[cur][t];
        if (t >= off) x += s[cur][t - off];
        s[cur ^ 1][t] = x;
        cur ^= 1;
        __syncthreads();
    }
    if (i < n) excl[i] = s[cur][t] - v;          // block-local exclusive
    if (t == 511) bsums[blockIdx.x] = s[cur][t]; // block total
}

__global__ __launch_bounds__(128) void scan_tops_kernel(const int* __restrict__ bsums,
                                                        int* __restrict__ btops, int nb) {
    __shared__ int s[2][128];
    int t = threadIdx.x;
    int v = (t < nb) ? bsums[t] : 0;
    s[0][t] = v;
    __syncthreads();
    int cur = 0;
    for (int off = 1; off < 128; off <<= 1) {
        int x = s[cur][t];
        if (t >= off) x += s[cur][t - off];
        s[cur ^ 1][t] = x;
        cur ^= 1;
        __syncthreads();
    }
    if (t < nb) btops[t] = s[cur][t] - v;        // exclusive over block sums
}

__global__ __launch_bounds__(512) void finalize_nodes_kernel(
        const int* __restrict__ excl, const int* __restrict__ btops,
        const int* __restrict__ cnt, int* __restrict__ row_ptr,
        int* __restrict__ cursor, float* __restrict__ dis, int n, int e) {
    int i = blockIdx.x * 512 + threadIdx.x;
    if (i < n) {
        int rp = excl[i] + btops[blockIdx.x];
        row_ptr[i] = rp;
        cursor[i]  = rp;
        // deg = edge indegree + 1 (self loop); always >= 1
        dis[i] = rsqrtf((float)(cnt[i] + 1));
    }
    if (i == 0) row_ptr[n] = e;
}

__global__ __launch_bounds__(256) void fill_csr_kernel(
        const int* __restrict__ src, const int* __restrict__ dst,
        int* __restrict__ cursor, int* __restrict__ csr_src, int e) {
    int i = blockIdx.x * 256 + threadIdx.x;
    if (i < e) {
        int s = src[i], d = dst[i];
        int pos = atomicAdd(&cursor[d], 1);
        csr_src[pos] = s;
    }
}

// ---------------- GEMM: C[M x NC] = act(A[M x K] @ W[K x NC] + bias) * rs[row] ----
// Register-tiled: thread = 8 rows x 4 cols. A reads are lane-broadcast (L1),
// W reads are coalesced float4 (L2-resident, <=64KB). VALU-bound by design.
// SCALE: multiply output row r by rs[r] (folds dis[src] for the GCN gather).

template <int K, int NC, bool RELU, bool BIAS, bool SCALE>
__global__ __launch_bounds__(256) void gemm_kernel(
        const float* __restrict__ A, const float* __restrict__ W,
        const float* __restrict__ bias, const float* __restrict__ rs,
        float* __restrict__ C, int M) {
    constexpr int CG  = NC / 4;      // col groups per row
    constexpr int RG  = 256 / CG;    // row-group threads
    constexpr int RPB = RG * 8;      // rows per block
    const int t  = threadIdx.x;
    const int tx = t % CG;
    const int ty = t / CG;
    const int c  = tx * 4;
    const int r0 = blockIdx.x * RPB + ty * 8;

    float4 bv = {0.f, 0.f, 0.f, 0.f};
    if (BIAS) bv = *(const float4*)&bias[c];

    if (r0 + 8 <= M) {
        float4 acc[8];
#pragma unroll
        for (int i = 0; i < 8; ++i) acc[i] = bv;
        const float* Ar = A + (size_t)r0 * K;
#pragma unroll 2
        for (int k0 = 0; k0 < K; k0 += 4) {
            float4 w0 = *(const float4*)&W[(size_t)(k0 + 0) * NC + c];
            float4 w1 = *(const float4*)&W[(size_t)(k0 + 1) * NC + c];
            float4 w2 = *(const float4*)&W[(size_t)(k0 + 2) * NC + c];
            float4 w3 = *(const float4*)&W[(size_t)(k0 + 3) * NC + c];
#pragma unroll
            for (int i = 0; i < 8; ++i) {
                float4 a = *(const float4*)&Ar[(size_t)i * K + k0];
                fma4(acc[i], a.x, w0);
                fma4(acc[i], a.y, w1);
                fma4(acc[i], a.z, w2);
                fma4(acc[i], a.w, w3);
            }
        }
        float* Cr = C + (size_t)r0 * NC + c;
#pragma unroll
        for (int i = 0; i < 8; ++i) {
            float4 v = acc[i];
            if (RELU) {
                v.x = fmaxf(v.x, 0.f); v.y = fmaxf(v.y, 0.f);
                v.z = fmaxf(v.z, 0.f); v.w = fmaxf(v.w, 0.f);
            }
            if (SCALE) {
                float s = rs[r0 + i];
                v.x *= s; v.y *= s; v.z *= s; v.w *= s;
            }
            *(float4*)&Cr[(size_t)i * NC] = v;
        }
    } else {
        for (int i = 0; i < 8; ++i) {
            int r = r0 + i;
            if (r >= M) break;
            float4 acc = bv;
            const float* Ar = A + (size_t)r * K;
            for (int k0 = 0; k0 < K; k0 += 4) {
                float4 a  = *(const float4*)&Ar[k0];
                float4 w0 = *(const float4*)&W[(size_t)(k0 + 0) * NC + c];
                float4 w1 = *(const float4*)&W[(size_t)(k0 + 1) * NC + c];
                float4 w2 = *(const float4*)&W[(size_t)(k0 + 2) * NC + c];
                float4 w3 = *(const float4*)&W[(size_t)(k0 + 3) * NC + c];
                fma4(acc, a.x, w0);
                fma4(acc, a.y, w1);
                fma4(acc, a.z, w2);
                fma4(acc, a.w, w3);
            }
            if (RELU) {
                acc.x = fmaxf(acc.x, 0.f); acc.y = fmaxf(acc.y, 0.f);
                acc.z = fmaxf(acc.z, 0.f); acc.w = fmaxf(acc.w, 0.f);
            }
            if (SCALE) {
                float s = rs[r];
                acc.x *= s; acc.y *= s; acc.z *= s; acc.w *= s;
            }
            *(float4*)&C[(size_t)r * NC + c] = acc;
        }
    }
}

// ---------------- Aggregation + bias + BN + ReLU + residual ----------------
// One 64-lane wave per node. float4 lanes: 32 lanes cover the full 128-f row.
// Half-wave 0 takes edges beg, beg+2, ...; half-wave 1 takes beg+1, beg+3 ...
// 2x unroll -> 4 independent 16B/lane gathers in flight (latency hiding).
// hwp rows are pre-scaled by dis[src]; epilogue multiplies by dis[dst].

__global__ __launch_bounds__(256) void agg_bn_kernel(
        const float* __restrict__ hwp, const int* __restrict__ row_ptr,
        const int* __restrict__ csr_src, const float* __restrict__ dis,
        const float* __restrict__ bc, const float* __restrict__ gamma_,
        const float* __restrict__ beta_, const float* __restrict__ rmean,
        const float* __restrict__ rvar,
        const float* __restrict__ h_in, float* __restrict__ h_out,
        int n, int residual) {
    int wid  = (blockIdx.x * 256 + threadIdx.x) >> 6;  // node id
    int lane = threadIdx.x & 63;
    if (wid >= n) return;
    const int half = lane >> 5;
    const int f    = (lane & 31) * 4;   // feature base, 32 lanes x float4 = 128

    float4 a0 = {0.f, 0.f, 0.f, 0.f};
    float4 a1 = {0.f, 0.f, 0.f, 0.f};
    // self-loop contribution hwp[wid] (added once, by half 0)
    if (half == 0) a0 = *(const float4*)(hwp + (size_t)wid * H_C + f);

    const int beg = row_ptr[wid], end = row_ptr[wid + 1];
    int e = beg + half;
    for (; e + 2 < end; e += 4) {
        int s0 = csr_src[e];
        int s1 = csr_src[e + 2];
        float4 r0 = *(const float4*)(hwp + (size_t)s0 * H_C + f);
        float4 r1 = *(const float4*)(hwp + (size_t)s1 * H_C + f);
        add4(a0, r0);
        add4(a1, r1);
    }
    if (e < end) {
        int s = csr_src[e];
        float4 r = *(const float4*)(hwp + (size_t)s * H_C + f);
        add4(a0, r);
    }
    add4(a0, a1);
    // combine the two half-waves (lane <-> lane^32)
    a0.x += __shfl_xor(a0.x, 32);
    a0.y += __shfl_xor(a0.y, 32);
    a0.z += __shfl_xor(a0.z, 32);
    a0.w += __shfl_xor(a0.w, 32);

    if (half == 0) {
        const float eps = 1e-5f;
        float dd = dis[wid];
        float4 b4 = *(const float4*)&bc[f];
        float4 g4 = *(const float4*)&gamma_[f];
        float4 be4 = *(const float4*)&beta_[f];
        float4 m4 = *(const float4*)&rmean[f];
        float4 v4 = *(const float4*)&rvar[f];
        float4 o;
        o.x = fmaf((fmaf(dd, a0.x, b4.x) - m4.x) * rsqrtf(v4.x + eps), g4.x, be4.x);
        o.y = fmaf((fmaf(dd, a0.y, b4.y) - m4.y) * rsqrtf(v4.y + eps), g4.y, be4.y);
        o.z = fmaf((fmaf(dd, a0.z, b4.z) - m4.z) * rsqrtf(v4.z + eps), g4.z, be4.z);
        o.w = fmaf((fmaf(dd, a0.w, b4.w) - m4.w) * rsqrtf(v4.w + eps), g4.w, be4.w);
        o.x = fmaxf(o.x, 0.f); o.y = fmaxf(o.y, 0.f);
        o.z = fmaxf(o.z, 0.f); o.w = fmaxf(o.w, 0.f);
        if (residual) {
            float4 r = *(const float4*)(h_in + (size_t)wid * H_C + f);
            add4(o, r);
        }
        *(float4*)(h_out + (size_t)wid * H_C + f) = o;
    }
}

// ---------------- Final dot: out[i] = t[i,:] . W2 + b2 ----------------

__global__ __launch_bounds__(256) void final_dot_kernel(
        const float* __restrict__ t, const float* __restrict__ W2,
        const float* __restrict__ b2, float* __restrict__ out, int n) {
    int wid  = (blockIdx.x * 256 + threadIdx.x) >> 6;
    int lane = threadIdx.x & 63;
    if (wid >= n) return;
    float v = t[(size_t)wid * 64 + lane] * W2[lane];
#pragma unroll
    for (int off = 32; off > 0; off >>= 1) v += __shfl_down(v, off, 64);
    if (lane == 0) out[wid] = v + b2[0];
}

// ---------------------------------------------------------------------------

extern "C" void kernel_launch(void* const* d_in, const int* in_sizes, int n_in,
                              void* d_out, int out_size, void* d_ws, size_t ws_size,
                              hipStream_t stream) {
    const float* x      = (const float*)d_in[0];
    const int*   ei     = (const int*)  d_in[1];
    const float* W_in   = (const float*)d_in[2];
    const float* b_in   = (const float*)d_in[3];
    const float* Wc     = (const float*)d_in[4];
    const float* bc     = (const float*)d_in[5];
    const float* gamma_ = (const float*)d_in[6];
    const float* beta_  = (const float*)d_in[7];
    const float* rmean  = (const float*)d_in[8];
    const float* rvar   = (const float*)d_in[9];
    const float* W1     = (const float*)d_in[10];
    const float* b1     = (const float*)d_in[11];
    const float* W2     = (const float*)d_in[12];
    const float* b2     = (const float*)d_in[13];
    float* out = (float*)d_out;

    const int M = in_sizes[0] / DIN_C;   // 50000 nodes
    const int E = in_sizes[1] / 2;       // 800000 edges
    const int* src = ei;
    const int* dst = ei + E;

    // Workspace carve-up (256B aligned)
    size_t off = 0;
    auto alloc = [&](size_t bytes) {
        void* p = (char*)d_ws + off;
        off += (bytes + 255) & ~(size_t)255;
        return p;
    };
    int*   cnt      = (int*)  alloc((size_t)M * 4);
    int*   excl     = (int*)  alloc((size_t)M * 4);
    int*   bsums    = (int*)  alloc(512);
    int*   btops    = (int*)  alloc(512);
    int*   row_ptr  = (int*)  alloc((size_t)(M + 1) * 4);
    int*   cursor   = (int*)  alloc((size_t)M * 4);
    float* dis      = (float*)alloc((size_t)M * 4);
    int*   csr_src  = (int*)  alloc((size_t)E * 4);
    float* hA       = (float*)alloc((size_t)M * H_C * 4);
    float* hB       = (float*)alloc((size_t)M * H_C * 4);
    float* hw       = (float*)alloc((size_t)M * H_C * 4);
    float* t_buf    = hw;  // reuse hw for the MLP hidden (dead by then)

    const int NB = (M + 511) / 512;  // scan blocks (98 for M=50000, <=128)

    // ---- CSR build ----
    hipMemsetAsync(cnt, 0, (size_t)M * 4, stream);
    count_deg_kernel<<<(E + 255) / 256, 256, 0, stream>>>(dst, cnt, E);
    scan_blocks_kernel<<<NB, 512, 0, stream>>>(cnt, excl, bsums, M);
    scan_tops_kernel<<<1, 128, 0, stream>>>(bsums, btops, NB);
    finalize_nodes_kernel<<<NB, 512, 0, stream>>>(excl, btops, cnt, row_ptr, cursor, dis, M, E);
    fill_csr_kernel<<<(E + 255) / 256, 256, 0, stream>>>(src, dst, cursor, csr_src, E);

    // ---- h0 = relu(x @ W_in + b_in) ----
    {
        constexpr int RPB = (256 / (H_C / 4)) * 8;  // 64 rows/block
        gemm_kernel<DIN_C, H_C, true, true, false><<<(M + RPB - 1) / RPB, 256, 0, stream>>>(
            x, W_in, b_in, nullptr, hA, M);
    }

    // ---- 3 GCN layers ----
    float* cur = hA;
    float* nxt = hB;
    for (int layer = 0; layer < 3; ++layer) {
        constexpr int RPB = (256 / (H_C / 4)) * 8;
        // hw' = (h @ Wc) * dis[row]  (dis[src] folded into gather operand)
        gemm_kernel<H_C, H_C, false, false, true><<<(M + RPB - 1) / RPB, 256, 0, stream>>>(
            cur, Wc + (size_t)layer * H_C * H_C, nullptr, dis, hw, M);
        agg_bn_kernel<<<(M * 64 + 255) / 256, 256, 0, stream>>>(
            hw, row_ptr, csr_src, dis,
            bc + (size_t)layer * H_C, gamma_ + (size_t)layer * H_C,
            beta_ + (size_t)layer * H_C, rmean + (size_t)layer * H_C,
            rvar + (size_t)layer * H_C,
            cur, nxt, M, layer > 0 ? 1 : 0);
        float* tmp = cur; cur = nxt; nxt = tmp;
    }

    // ---- head: out = relu(h @ W1 + b1) @ W2 + b2 ----
    {
        constexpr int RPB = (256 / (64 / 4)) * 8;  // 128 rows/block
        gemm_kernel<H_C, 64, true, true, false><<<(M + RPB - 1) / RPB, 256, 0, stream>>>(
            cur, W1, b1, nullptr, t_buf, M);
    }
    final_dot_kernel<<<(M * 64 + 255) / 256, 256, 0, stream>>>(t_buf, W2, b2, out, M);
}

// Round 9
// 565.724 us; speedup vs baseline: 1.1762x; 1.0322x over previous
//
#include <hip/hip_runtime.h>

// ---------------------------------------------------------------------------
// AtomExposureGNN: 3-layer GCN (N=50000, E=800000, DIN=64, H=128) + MLP head
// R5: agg gather unrolled to 8 loads in flight (4-way per half-wave, was 2);
//     MLP head fused into one kernel (gemm tile + W2 dot + shfl reduce);
//     GEMM K-loop unroll 2->4.
// R3: float4-lane gather, separable norm folded into GEMM epilogue.
// ---------------------------------------------------------------------------

__device__ __forceinline__ void fma4(float4& acc, float s, const float4& v) {
    acc.x = fmaf(s, v.x, acc.x);
    acc.y = fmaf(s, v.y, acc.y);
    acc.z = fmaf(s, v.z, acc.z);
    acc.w = fmaf(s, v.w, acc.w);
}
__device__ __forceinline__ void add4(float4& acc, const float4& v) {
    acc.x += v.x; acc.y += v.y; acc.z += v.z; acc.w += v.w;
}

constexpr int DIN_C = 64;
constexpr int H_C = 128;

// ---------------- CSR construction ----------------

__global__ __launch_bounds__(256) void count_deg_kernel(const int* __restrict__ dst,
                                                        int* __restrict__ cnt, int e) {
    int i = blockIdx.x * 256 + threadIdx.x;
    if (i < e) atomicAdd(&cnt[dst[i]], 1);
}

__global__ __launch_bounds__(512) void scan_blocks_kernel(const int* __restrict__ cnt,
                                                          int* __restrict__ excl,
                                                          int* __restrict__ bsums, int n) {
    __shared__ int s[2][512];
    int t = threadIdx.x;
    int i = blockIdx.x * 512 + t;
    int v = (i < n) ? cnt[i] : 0;
    s[0][t] = v;
    __syncthreads();
    int cur = 0;
    for (int off = 1; off < 512; off <<= 1) {
        int x = s[cur][t];
        if (t >= off) x += s[cur][t - off];
        s[cur ^ 1][t] = x;
        cur ^= 1;
        __syncthreads();
    }
    if (i < n) excl[i] = s[cur][t] - v;          // block-local exclusive
    if (t == 511) bsums[blockIdx.x] = s[cur][t]; // block total
}

__global__ __launch_bounds__(128) void scan_tops_kernel(const int* __restrict__ bsums,
                                                        int* __restrict__ btops, int nb) {
    __shared__ int s[2][128];
    int t = threadIdx.x;
    int v = (t < nb) ? bsums[t] : 0;
    s[0][t] = v;
    __syncthreads();
    int cur = 0;
    for (int off = 1; off < 128; off <<= 1) {
        int x = s[cur][t];
        if (t >= off) x += s[cur][t - off];
        s[cur ^ 1][t] = x;
        cur ^= 1;
        __syncthreads();
    }
    if (t < nb) btops[t] = s[cur][t] - v;        // exclusive over block sums
}

__global__ __launch_bounds__(512) void finalize_nodes_kernel(
        const int* __restrict__ excl, const int* __restrict__ btops,
        const int* __restrict__ cnt, int* __restrict__ row_ptr,
        int* __restrict__ cursor, float* __restrict__ dis, int n, int e) {
    int i = blockIdx.x * 512 + threadIdx.x;
    if (i < n) {
        int rp = excl[i] + btops[blockIdx.x];
        row_ptr[i] = rp;
        cursor[i]  = rp;
        // deg = edge indegree + 1 (self loop); always >= 1
        dis[i] = rsqrtf((float)(cnt[i] + 1));
    }
    if (i == 0) row_ptr[n] = e;
}

__global__ __launch_bounds__(256) void fill_csr_kernel(
        const int* __restrict__ src, const int* __restrict__ dst,
        int* __restrict__ cursor, int* __restrict__ csr_src, int e) {
    int i = blockIdx.x * 256 + threadIdx.x;
    if (i < e) {
        int s = src[i], d = dst[i];
        int pos = atomicAdd(&cursor[d], 1);
        csr_src[pos] = s;
    }
}

// ---------------- GEMM: C[M x NC] = act(A[M x K] @ W[K x NC] + bias) * rs[row] ----
// Register-tiled: thread = 8 rows x 4 cols. A reads are lane-broadcast (L1),
// W reads are coalesced float4 (L2-resident, <=64KB). VALU-bound by design.
// SCALE: multiply output row r by rs[r] (folds dis[src] for the GCN gather).

template <int K, int NC, bool RELU, bool BIAS, bool SCALE>
__global__ __launch_bounds__(256) void gemm_kernel(
        const float* __restrict__ A, const float* __restrict__ W,
        const float* __restrict__ bias, const float* __restrict__ rs,
        float* __restrict__ C, int M) {
    constexpr int CG  = NC / 4;      // col groups per row
    constexpr int RG  = 256 / CG;    // row-group threads
    constexpr int RPB = RG * 8;      // rows per block
    const int t  = threadIdx.x;
    const int tx = t % CG;
    const int ty = t / CG;
    const int c  = tx * 4;
    const int r0 = blockIdx.x * RPB + ty * 8;

    float4 bv = {0.f, 0.f, 0.f, 0.f};
    if (BIAS) bv = *(const float4*)&bias[c];

    if (r0 + 8 <= M) {
        float4 acc[8];
#pragma unroll
        for (int i = 0; i < 8; ++i) acc[i] = bv;
        const float* Ar = A + (size_t)r0 * K;
#pragma unroll 4
        for (int k0 = 0; k0 < K; k0 += 4) {
            float4 w0 = *(const float4*)&W[(size_t)(k0 + 0) * NC + c];
            float4 w1 = *(const float4*)&W[(size_t)(k0 + 1) * NC + c];
            float4 w2 = *(const float4*)&W[(size_t)(k0 + 2) * NC + c];
            float4 w3 = *(const float4*)&W[(size_t)(k0 + 3) * NC + c];
#pragma unroll
            for (int i = 0; i < 8; ++i) {
                float4 a = *(const float4*)&Ar[(size_t)i * K + k0];
                fma4(acc[i], a.x, w0);
                fma4(acc[i], a.y, w1);
                fma4(acc[i], a.z, w2);
                fma4(acc[i], a.w, w3);
            }
        }
        float* Cr = C + (size_t)r0 * NC + c;
#pragma unroll
        for (int i = 0; i < 8; ++i) {
            float4 v = acc[i];
            if (RELU) {
                v.x = fmaxf(v.x, 0.f); v.y = fmaxf(v.y, 0.f);
                v.z = fmaxf(v.z, 0.f); v.w = fmaxf(v.w, 0.f);
            }
            if (SCALE) {
                float s = rs[r0 + i];
                v.x *= s; v.y *= s; v.z *= s; v.w *= s;
            }
            *(float4*)&Cr[(size_t)i * NC] = v;
        }
    } else {
        for (int i = 0; i < 8; ++i) {
            int r = r0 + i;
            if (r >= M) break;
            float4 acc = bv;
            const float* Ar = A + (size_t)r * K;
            for (int k0 = 0; k0 < K; k0 += 4) {
                float4 a  = *(const float4*)&Ar[k0];
                float4 w0 = *(const float4*)&W[(size_t)(k0 + 0) * NC + c];
                float4 w1 = *(const float4*)&W[(size_t)(k0 + 1) * NC + c];
                float4 w2 = *(const float4*)&W[(size_t)(k0 + 2) * NC + c];
                float4 w3 = *(const float4*)&W[(size_t)(k0 + 3) * NC + c];
                fma4(acc, a.x, w0);
                fma4(acc, a.y, w1);
                fma4(acc, a.z, w2);
                fma4(acc, a.w, w3);
            }
            if (RELU) {
                acc.x = fmaxf(acc.x, 0.f); acc.y = fmaxf(acc.y, 0.f);
                acc.z = fmaxf(acc.z, 0.f); acc.w = fmaxf(acc.w, 0.f);
            }
            if (SCALE) {
                float s = rs[r];
                acc.x *= s; acc.y *= s; acc.z *= s; acc.w *= s;
            }
            *(float4*)&C[(size_t)r * NC + c] = acc;
        }
    }
}

// ---------------- Fused MLP head: out = relu(h @ W1 + b1) @ W2 + b2 ----------------
// Same 8x4 register tile (K=128, NC=64, CG=16, RPB=128); epilogue dots with
// W2 and reduces the 16-lane column group via shfl_xor. Removes the t_buf
// round-trip and the separate final_dot kernel.

__global__ __launch_bounds__(256) void head_kernel(
        const float* __restrict__ A, const float* __restrict__ W1,
        const float* __restrict__ b1, const float* __restrict__ W2,
        const float* __restrict__ b2, float* __restrict__ out, int M) {
    constexpr int K = 128, NC = 64;
    constexpr int CG  = NC / 4;      // 16 lanes cover the 64 cols
    constexpr int RPB = (256 / CG) * 8;  // 128 rows per block
    const int t  = threadIdx.x;
    const int tx = t % CG;
    const int ty = t / CG;
    const int c  = tx * 4;
    const int r0 = blockIdx.x * RPB + ty * 8;

    float4 bv = *(const float4*)&b1[c];
    float4 w2v = *(const float4*)&W2[c];
    float b2v = b2[0];

    float part[8];
    if (r0 + 8 <= M) {
        float4 acc[8];
#pragma unroll
        for (int i = 0; i < 8; ++i) acc[i] = bv;
        const float* Ar = A + (size_t)r0 * K;
#pragma unroll 4
        for (int k0 = 0; k0 < K; k0 += 4) {
            float4 w0 = *(const float4*)&W1[(size_t)(k0 + 0) * NC + c];
            float4 w1 = *(const float4*)&W1[(size_t)(k0 + 1) * NC + c];
            float4 w2 = *(const float4*)&W1[(size_t)(k0 + 2) * NC + c];
            float4 w3 = *(const float4*)&W1[(size_t)(k0 + 3) * NC + c];
#pragma unroll
            for (int i = 0; i < 8; ++i) {
                float4 a = *(const float4*)&Ar[(size_t)i * K + k0];
                fma4(acc[i], a.x, w0);
                fma4(acc[i], a.y, w1);
                fma4(acc[i], a.z, w2);
                fma4(acc[i], a.w, w3);
            }
        }
#pragma unroll
        for (int i = 0; i < 8; ++i) {
            float4 v = acc[i];
            v.x = fmaxf(v.x, 0.f); v.y = fmaxf(v.y, 0.f);
            v.z = fmaxf(v.z, 0.f); v.w = fmaxf(v.w, 0.f);
            part[i] = v.x * w2v.x + v.y * w2v.y + v.z * w2v.z + v.w * w2v.w;
        }
    } else {
#pragma unroll
        for (int i = 0; i < 8; ++i) {
            int r = r0 + i;
            part[i] = 0.f;
            if (r < M) {
                float4 acc = bv;
                const float* Ar = A + (size_t)r * K;
                for (int k0 = 0; k0 < K; k0 += 4) {
                    float4 a  = *(const float4*)&Ar[k0];
                    float4 w0 = *(const float4*)&W1[(size_t)(k0 + 0) * NC + c];
                    float4 w1 = *(const float4*)&W1[(size_t)(k0 + 1) * NC + c];
                    float4 w2 = *(const float4*)&W1[(size_t)(k0 + 2) * NC + c];
                    float4 w3 = *(const float4*)&W1[(size_t)(k0 + 3) * NC + c];
                    fma4(acc, a.x, w0);
                    fma4(acc, a.y, w1);
                    fma4(acc, a.z, w2);
                    fma4(acc, a.w, w3);
                }
                acc.x = fmaxf(acc.x, 0.f); acc.y = fmaxf(acc.y, 0.f);
                acc.z = fmaxf(acc.z, 0.f); acc.w = fmaxf(acc.w, 0.f);
                part[i] = acc.x * w2v.x + acc.y * w2v.y + acc.z * w2v.z + acc.w * w2v.w;
            }
        }
    }
    // reduce across the 16-lane column group (lanes ty*16+tx within the wave)
#pragma unroll
    for (int i = 0; i < 8; ++i) {
        float v = part[i];
        v += __shfl_xor(v, 1);
        v += __shfl_xor(v, 2);
        v += __shfl_xor(v, 4);
        v += __shfl_xor(v, 8);
        part[i] = v;
    }
    if (tx == 0) {
#pragma unroll
        for (int i = 0; i < 8; ++i) {
            int r = r0 + i;
            if (r < M) out[r] = part[i] + b2v;
        }
    }
}

// ---------------- Aggregation + bias + BN + ReLU + residual ----------------
// One 64-lane wave per node. float4 lanes: 32 lanes cover the full 128-f row.
// Half-wave h takes edges beg+h, beg+h+2, ...; 4x unroll -> 8 independent
// 16B/lane gathers in flight. hwp rows pre-scaled by dis[src]; epilogue
// multiplies by dis[dst]. Cross-half combine via shfl_xor(,32).

__global__ __launch_bounds__(256) void agg_bn_kernel(
        const float* __restrict__ hwp, const int* __restrict__ row_ptr,
        const int* __restrict__ csr_src, const float* __restrict__ dis,
        const float* __restrict__ bc, const float* __restrict__ gamma_,
        const float* __restrict__ beta_, const float* __restrict__ rmean,
        const float* __restrict__ rvar,
        const float* __restrict__ h_in, float* __restrict__ h_out,
        int n, int residual) {
    int wid  = (blockIdx.x * 256 + threadIdx.x) >> 6;  // node id
    int lane = threadIdx.x & 63;
    if (wid >= n) return;
    const int half = lane >> 5;
    const int f    = (lane & 31) * 4;   // feature base, 32 lanes x float4 = 128

    float4 a0 = {0.f, 0.f, 0.f, 0.f};
    float4 a1 = {0.f, 0.f, 0.f, 0.f};
    float4 a2 = {0.f, 0.f, 0.f, 0.f};
    float4 a3 = {0.f, 0.f, 0.f, 0.f};
    // self-loop contribution hwp[wid] (added once, by half 0)
    if (half == 0) a0 = *(const float4*)(hwp + (size_t)wid * H_C + f);

    const int beg = row_ptr[wid], end = row_ptr[wid + 1];
    int e = beg + half;
    // 4-way unroll per half: 8 gathers in flight wave-wide
    for (; e + 6 < end; e += 8) {
        int s0 = csr_src[e];
        int s1 = csr_src[e + 2];
        int s2 = csr_src[e + 4];
        int s3 = csr_src[e + 6];
        float4 r0 = *(const float4*)(hwp + (size_t)s0 * H_C + f);
        float4 r1 = *(const float4*)(hwp + (size_t)s1 * H_C + f);
        float4 r2 = *(const float4*)(hwp + (size_t)s2 * H_C + f);
        float4 r3 = *(const float4*)(hwp + (size_t)s3 * H_C + f);
        add4(a0, r0);
        add4(a1, r1);
        add4(a2, r2);
        add4(a3, r3);
    }
    for (; e + 2 < end; e += 4) {
        int s0 = csr_src[e];
        int s1 = csr_src[e + 2];
        float4 r0 = *(const float4*)(hwp + (size_t)s0 * H_C + f);
        float4 r1 = *(const float4*)(hwp + (size_t)s1 * H_C + f);
        add4(a0, r0);
        add4(a1, r1);
    }
    if (e < end) {
        int s = csr_src[e];
        float4 r = *(const float4*)(hwp + (size_t)s * H_C + f);
        add4(a0, r);
    }
    add4(a0, a2);
    add4(a1, a3);
    add4(a0, a1);
    // combine the two half-waves (lane <-> lane^32)
    a0.x += __shfl_xor(a0.x, 32);
    a0.y += __shfl_xor(a0.y, 32);
    a0.z += __shfl_xor(a0.z, 32);
    a0.w += __shfl_xor(a0.w, 32);

    if (half == 0) {
        const float eps = 1e-5f;
        float dd = dis[wid];
        float4 b4 = *(const float4*)&bc[f];
        float4 g4 = *(const float4*)&gamma_[f];
        float4 be4 = *(const float4*)&beta_[f];
        float4 m4 = *(const float4*)&rmean[f];
        float4 v4 = *(const float4*)&rvar[f];
        float4 o;
        o.x = fmaf((fmaf(dd, a0.x, b4.x) - m4.x) * rsqrtf(v4.x + eps), g4.x, be4.x);
        o.y = fmaf((fmaf(dd, a0.y, b4.y) - m4.y) * rsqrtf(v4.y + eps), g4.y, be4.y);
        o.z = fmaf((fmaf(dd, a0.z, b4.z) - m4.z) * rsqrtf(v4.z + eps), g4.z, be4.z);
        o.w = fmaf((fmaf(dd, a0.w, b4.w) - m4.w) * rsqrtf(v4.w + eps), g4.w, be4.w);
        o.x = fmaxf(o.x, 0.f); o.y = fmaxf(o.y, 0.f);
        o.z = fmaxf(o.z, 0.f); o.w = fmaxf(o.w, 0.f);
        if (residual) {
            float4 r = *(const float4*)(h_in + (size_t)wid * H_C + f);
            add4(o, r);
        }
        *(float4*)(h_out + (size_t)wid * H_C + f) = o;
    }
}

// ---------------------------------------------------------------------------

extern "C" void kernel_launch(void* const* d_in, const int* in_sizes, int n_in,
                              void* d_out, int out_size, void* d_ws, size_t ws_size,
                              hipStream_t stream) {
    const float* x      = (const float*)d_in[0];
    const int*   ei     = (const int*)  d_in[1];
    const float* W_in   = (const float*)d_in[2];
    const float* b_in   = (const float*)d_in[3];
    const float* Wc     = (const float*)d_in[4];
    const float* bc     = (const float*)d_in[5];
    const float* gamma_ = (const float*)d_in[6];
    const float* beta_  = (const float*)d_in[7];
    const float* rmean  = (const float*)d_in[8];
    const float* rvar   = (const float*)d_in[9];
    const float* W1     = (const float*)d_in[10];
    const float* b1     = (const float*)d_in[11];
    const float* W2     = (const float*)d_in[12];
    const float* b2     = (const float*)d_in[13];
    float* out = (float*)d_out;

    const int M = in_sizes[0] / DIN_C;   // 50000 nodes
    const int E = in_sizes[1] / 2;       // 800000 edges
    const int* src = ei;
    const int* dst = ei + E;

    // Workspace carve-up (256B aligned)
    size_t off = 0;
    auto alloc = [&](size_t bytes) {
        void* p = (char*)d_ws + off;
        off += (bytes + 255) & ~(size_t)255;
        return p;
    };
    int*   cnt      = (int*)  alloc((size_t)M * 4);
    int*   excl     = (int*)  alloc((size_t)M * 4);
    int*   bsums    = (int*)  alloc(512);
    int*   btops    = (int*)  alloc(512);
    int*   row_ptr  = (int*)  alloc((size_t)(M + 1) * 4);
    int*   cursor   = (int*)  alloc((size_t)M * 4);
    float* dis      = (float*)alloc((size_t)M * 4);
    int*   csr_src  = (int*)  alloc((size_t)E * 4);
    float* hA       = (float*)alloc((size_t)M * H_C * 4);
    float* hB       = (float*)alloc((size_t)M * H_C * 4);
    float* hw       = (float*)alloc((size_t)M * H_C * 4);

    const int NB = (M + 511) / 512;  // scan blocks (98 for M=50000, <=128)

    // ---- CSR build ----
    hipMemsetAsync(cnt, 0, (size_t)M * 4, stream);
    count_deg_kernel<<<(E + 255) / 256, 256, 0, stream>>>(dst, cnt, E);
    scan_blocks_kernel<<<NB, 512, 0, stream>>>(cnt, excl, bsums, M);
    scan_tops_kernel<<<1, 128, 0, stream>>>(bsums, btops, NB);
    finalize_nodes_kernel<<<NB, 512, 0, stream>>>(excl, btops, cnt, row_ptr, cursor, dis, M, E);
    fill_csr_kernel<<<(E + 255) / 256, 256, 0, stream>>>(src, dst, cursor, csr_src, E);

    // ---- h0 = relu(x @ W_in + b_in) ----
    {
        constexpr int RPB = (256 / (H_C / 4)) * 8;  // 64 rows/block
        gemm_kernel<DIN_C, H_C, true, true, false><<<(M + RPB - 1) / RPB, 256, 0, stream>>>(
            x, W_in, b_in, nullptr, hA, M);
    }

    // ---- 3 GCN layers ----
    float* cur = hA;
    float* nxt = hB;
    for (int layer = 0; layer < 3; ++layer) {
        constexpr int RPB = (256 / (H_C / 4)) * 8;
        // hw' = (h @ Wc) * dis[row]  (dis[src] folded into gather operand)
        gemm_kernel<H_C, H_C, false, false, true><<<(M + RPB - 1) / RPB, 256, 0, stream>>>(
            cur, Wc + (size_t)layer * H_C * H_C, nullptr, dis, hw, M);
        agg_bn_kernel<<<(M * 64 + 255) / 256, 256, 0, stream>>>(
            hw, row_ptr, csr_src, dis,
            bc + (size_t)layer * H_C, gamma_ + (size_t)layer * H_C,
            beta_ + (size_t)layer * H_C, rmean + (size_t)layer * H_C,
            rvar + (size_t)layer * H_C,
            cur, nxt, M, layer > 0 ? 1 : 0);
        float* tmp = cur; cur = nxt; nxt = tmp;
    }

    // ---- fused head: out = relu(h @ W1 + b1) @ W2 + b2 ----
    {
        constexpr int RPB = (256 / (64 / 4)) * 8;  // 128 rows/block
        head_kernel<<<(M + RPB - 1) / RPB, 256, 0, stream>>>(
            cur, W1, b1, W2, b2, out, M);
    }
}

// Round 12
// 525.769 us; speedup vs baseline: 1.2656x; 1.0760x over previous
//
#include <hip/hip_runtime.h>

// ---------------------------------------------------------------------------
// AtomExposureGNN: 3-layer GCN (N=50000, E=800000, DIN=64, H=128) + MLP head
// R9: GEMMs moved to MFMA bf16x2-split (ah*bh + ah*bl + al*bh, fp32 acc):
//     ~fp32 precision at ~5x the fp32 VALU rate. W pre-split/transposed to
//     WT_hi/lo[n][k] (bf16) by a tiny per-call kernel; A split in-register.
//     agg (at its ~3.75TB/s random-gather ceiling), head, CSR unchanged.
// R5: agg 8 loads in flight; fused MLP head.
// R3: float4-lane gather, separable norm folded into GEMM epilogue.
// ---------------------------------------------------------------------------

typedef unsigned short ushort_t;
typedef __attribute__((ext_vector_type(8))) short bf16x8;
typedef __attribute__((ext_vector_type(4))) float f32x4;

__device__ __forceinline__ void fma4(float4& acc, float s, const float4& v) {
    acc.x = fmaf(s, v.x, acc.x);
    acc.y = fmaf(s, v.y, acc.y);
    acc.z = fmaf(s, v.z, acc.z);
    acc.w = fmaf(s, v.w, acc.w);
}
__device__ __forceinline__ void add4(float4& acc, const float4& v) {
    acc.x += v.x; acc.y += v.y; acc.z += v.z; acc.w += v.w;
}

// bf16 round-to-nearest-even from fp32, and back
__device__ __forceinline__ ushort_t f2bf(float x) {
    union { float f; unsigned u; } v; v.f = x;
    unsigned r = v.u + 0x7FFFu + ((v.u >> 16) & 1u);
    return (ushort_t)(r >> 16);
}
__device__ __forceinline__ float bf2f(ushort_t h) {
    union { unsigned u; float f; } v; v.u = ((unsigned)h) << 16;
    return v.f;
}

constexpr int DIN_C = 64;
constexpr int H_C = 128;

// ---------------- CSR construction ----------------

__global__ __launch_bounds__(256) void count_deg_kernel(const int* __restrict__ dst,
                                                        int* __restrict__ cnt, int e) {
    int i = blockIdx.x * 256 + threadIdx.x;
    if (i < e) atomicAdd(&cnt[dst[i]], 1);
}

__global__ __launch_bounds__(512) void scan_blocks_kernel(const int* __restrict__ cnt,
                                                          int* __restrict__ excl,
                                                          int* __restrict__ bsums, int n) {
    __shared__ int s[2][512];
    int t = threadIdx.x;
    int i = blockIdx.x * 512 + t;
    int v = (i < n) ? cnt[i] : 0;
    s[0][t] = v;
    __syncthreads();
    int cur = 0;
    for (int off = 1; off < 512; off <<= 1) {
        int x = s[cur][t];
        if (t >= off) x += s[cur][t - off];
        s[cur ^ 1][t] = x;
        cur ^= 1;
        __syncthreads();
    }
    if (i < n) excl[i] = s[cur][t] - v;          // block-local exclusive
    if (t == 511) bsums[blockIdx.x] = s[cur][t]; // block total
}

__global__ __launch_bounds__(128) void scan_tops_kernel(const int* __restrict__ bsums,
                                                        int* __restrict__ btops, int nb) {
    __shared__ int s[2][128];
    int t = threadIdx.x;
    int v = (t < nb) ? bsums[t] : 0;
    s[0][t] = v;
    __syncthreads();
    int cur = 0;
    for (int off = 1; off < 128; off <<= 1) {
        int x = s[cur][t];
        if (t >= off) x += s[cur][t - off];
        s[cur ^ 1][t] = x;
        cur ^= 1;
        __syncthreads();
    }
    if (t < nb) btops[t] = s[cur][t] - v;        // exclusive over block sums
}

__global__ __launch_bounds__(512) void finalize_nodes_kernel(
        const int* __restrict__ excl, const int* __restrict__ btops,
        const int* __restrict__ cnt, int* __restrict__ row_ptr,
        int* __restrict__ cursor, float* __restrict__ dis, int n, int e) {
    int i = blockIdx.x * 512 + threadIdx.x;
    if (i < n) {
        int rp = excl[i] + btops[blockIdx.x];
        row_ptr[i] = rp;
        cursor[i]  = rp;
        dis[i] = rsqrtf((float)(cnt[i] + 1));  // deg = indegree + self loop
    }
    if (i == 0) row_ptr[n] = e;
}

__global__ __launch_bounds__(256) void fill_csr_kernel(
        const int* __restrict__ src, const int* __restrict__ dst,
        int* __restrict__ cursor, int* __restrict__ csr_src, int e) {
    int i = blockIdx.x * 256 + threadIdx.x;
    if (i < e) {
        int s = src[i], d = dst[i];
        int pos = atomicAdd(&cursor[d], 1);
        csr_src[pos] = s;
    }
}

// ---------------- W split+transpose: fp32 W[k][n] -> bf16 WT_hi/lo[n][k] ------
// Layer weights Wc[3][128][128] and input W_in[64][128]. Tiny (57K elements).

__global__ __launch_bounds__(256) void wsplit_kernel(
        const float* __restrict__ Wc, const float* __restrict__ W_in,
        ushort_t* __restrict__ lt_hi, ushort_t* __restrict__ lt_lo,   // [3][128][128]
        ushort_t* __restrict__ it_hi, ushort_t* __restrict__ it_lo) { // [128][64]
    int i = blockIdx.x * 256 + threadIdx.x;
    if (i < 3 * 128 * 128) {
        int m = i >> 14, rem = i & 16383;
        int k = rem >> 7, n = rem & 127;
        float v = Wc[i];
        ushort_t h = f2bf(v);
        ushort_t l = f2bf(v - bf2f(h));
        lt_hi[(m << 14) + n * 128 + k] = h;
        lt_lo[(m << 14) + n * 128 + k] = l;
    } else {
        int j = i - 3 * 128 * 128;
        if (j < 64 * 128) {
            int k = j >> 7, n = j & 127;
            float v = W_in[j];
            ushort_t h = f2bf(v);
            ushort_t l = f2bf(v - bf2f(h));
            it_hi[n * 64 + k] = h;
            it_lo[n * 64 + k] = l;
        }
    }
}

// ---------------- MFMA GEMM: C[M x 128] = act(A[M x K] @ W + bias) * rs[row] --
// bf16x2 split: acc += ah*bh + ah*bl + al*bh (al*bl ~2^-16, dropped).
// 4 waves/block; wave = 16 rows x 128 cols = 8 mfma tiles of 16x16, K in
// steps of 32. A fragment: lane l holds A[r0 + (l&15)][kb*32 + (l>>4)*8 + j].
// B fragment from WT[n][k]: lane l holds WT[nt*16 + (l&15)][kb*32 + (l>>4)*8 + j].
// C/D: row = (l>>4)*4 + reg, col = l&15 (verified mapping).

template <int KSTEPS, bool RELU, bool BIAS, bool SCALE>
__global__ __launch_bounds__(256) void gemm_mfma_kernel(
        const float* __restrict__ A, const ushort_t* __restrict__ wt_hi,
        const ushort_t* __restrict__ wt_lo, const float* __restrict__ bias,
        const float* __restrict__ rs, float* __restrict__ C, int M) {
    constexpr int K = KSTEPS * 32;
    const int tid  = threadIdx.x;
    const int wid  = tid >> 6;
    const int lane = tid & 63;
    const int lo16 = lane & 15;
    const int hi4  = lane >> 4;            // 0..3
    const int r0   = blockIdx.x * 64 + wid * 16;

    f32x4 acc[8];
#pragma unroll
    for (int nt = 0; nt < 8; ++nt) {
        float b = BIAS ? bias[nt * 16 + lo16] : 0.f;
        acc[nt] = (f32x4){b, b, b, b};
    }

    int ar = r0 + lo16;                    // A-load row (clamped for tail)
    if (ar > M - 1) ar = M - 1;
    const float* Arow = A + (size_t)ar * K;

#pragma unroll
    for (int kb = 0; kb < KSTEPS; ++kb) {
        const float4* ap = (const float4*)(Arow + kb * 32 + hi4 * 8);
        float4 a0 = ap[0], a1 = ap[1];
        float av[8] = {a0.x, a0.y, a0.z, a0.w, a1.x, a1.y, a1.z, a1.w};
        bf16x8 afh, afl;
#pragma unroll
        for (int j = 0; j < 8; ++j) {
            ushort_t h = f2bf(av[j]);
            afh[j] = (short)h;
            afl[j] = (short)f2bf(av[j] - bf2f(h));
        }
        const int kof = kb * 32 + hi4 * 8;
#pragma unroll
        for (int nt = 0; nt < 8; ++nt) {
            const size_t boff = (size_t)(nt * 16 + lo16) * K + kof;
            bf16x8 bfh = *(const bf16x8*)(wt_hi + boff);
            bf16x8 bfl = *(const bf16x8*)(wt_lo + boff);
            acc[nt] = __builtin_amdgcn_mfma_f32_16x16x32_bf16(afh, bfh, acc[nt], 0, 0, 0);
            acc[nt] = __builtin_amdgcn_mfma_f32_16x16x32_bf16(afh, bfl, acc[nt], 0, 0, 0);
            acc[nt] = __builtin_amdgcn_mfma_f32_16x16x32_bf16(afl, bfh, acc[nt], 0, 0, 0);
        }
    }

#pragma unroll
    for (int reg = 0; reg < 4; ++reg) {
        int r = r0 + hi4 * 4 + reg;
        if (r < M) {
            float s = SCALE ? rs[r] : 1.f;
#pragma unroll
            for (int nt = 0; nt < 8; ++nt) {
                float v = acc[nt][reg];
                if (RELU) v = fmaxf(v, 0.f);
                C[(size_t)r * 128 + nt * 16 + lo16] = SCALE ? v * s : v;
            }
        }
    }
}

// ---------------- Fused MLP head: out = relu(h @ W1 + b1) @ W2 + b2 ----------
// fp32 register tile 8 rows x 4 cols + W2 dot + shfl_xor reduce (16-lane grp).

__global__ __launch_bounds__(256) void head_kernel(
        const float* __restrict__ A, const float* __restrict__ W1,
        const float* __restrict__ b1, const float* __restrict__ W2,
        const float* __restrict__ b2, float* __restrict__ out, int M) {
    constexpr int K = 128, NC = 64;
    constexpr int CG  = NC / 4;
    constexpr int RPB = (256 / CG) * 8;  // 128 rows per block
    const int t  = threadIdx.x;
    const int tx = t % CG;
    const int ty = t / CG;
    const int c  = tx * 4;
    const int r0 = blockIdx.x * RPB + ty * 8;

    float4 bv = *(const float4*)&b1[c];
    float4 w2v = *(const float4*)&W2[c];
    float b2v = b2[0];

    float part[8];
    if (r0 + 8 <= M) {
        float4 acc[8];
#pragma unroll
        for (int i = 0; i < 8; ++i) acc[i] = bv;
        const float* Ar = A + (size_t)r0 * K;
#pragma unroll 4
        for (int k0 = 0; k0 < K; k0 += 4) {
            float4 w0 = *(const float4*)&W1[(size_t)(k0 + 0) * NC + c];
            float4 w1 = *(const float4*)&W1[(size_t)(k0 + 1) * NC + c];
            float4 w2 = *(const float4*)&W1[(size_t)(k0 + 2) * NC + c];
            float4 w3 = *(const float4*)&W1[(size_t)(k0 + 3) * NC + c];
#pragma unroll
            for (int i = 0; i < 8; ++i) {
                float4 a = *(const float4*)&Ar[(size_t)i * K + k0];
                fma4(acc[i], a.x, w0);
                fma4(acc[i], a.y, w1);
                fma4(acc[i], a.z, w2);
                fma4(acc[i], a.w, w3);
            }
        }
#pragma unroll
        for (int i = 0; i < 8; ++i) {
            float4 v = acc[i];
            v.x = fmaxf(v.x, 0.f); v.y = fmaxf(v.y, 0.f);
            v.z = fmaxf(v.z, 0.f); v.w = fmaxf(v.w, 0.f);
            part[i] = v.x * w2v.x + v.y * w2v.y + v.z * w2v.z + v.w * w2v.w;
        }
    } else {
#pragma unroll
        for (int i = 0; i < 8; ++i) {
            int r = r0 + i;
            part[i] = 0.f;
            if (r < M) {
                float4 acc = bv;
                const float* Ar = A + (size_t)r * K;
                for (int k0 = 0; k0 < K; k0 += 4) {
                    float4 a  = *(const float4*)&Ar[k0];
                    float4 w0 = *(const float4*)&W1[(size_t)(k0 + 0) * NC + c];
                    float4 w1 = *(const float4*)&W1[(size_t)(k0 + 1) * NC + c];
                    float4 w2 = *(const float4*)&W1[(size_t)(k0 + 2) * NC + c];
                    float4 w3 = *(const float4*)&W1[(size_t)(k0 + 3) * NC + c];
                    fma4(acc, a.x, w0);
                    fma4(acc, a.y, w1);
                    fma4(acc, a.z, w2);
                    fma4(acc, a.w, w3);
                }
                acc.x = fmaxf(acc.x, 0.f); acc.y = fmaxf(acc.y, 0.f);
                acc.z = fmaxf(acc.z, 0.f); acc.w = fmaxf(acc.w, 0.f);
                part[i] = acc.x * w2v.x + acc.y * w2v.y + acc.z * w2v.z + acc.w * w2v.w;
            }
        }
    }
#pragma unroll
    for (int i = 0; i < 8; ++i) {
        float v = part[i];
        v += __shfl_xor(v, 1);
        v += __shfl_xor(v, 2);
        v += __shfl_xor(v, 4);
        v += __shfl_xor(v, 8);
        part[i] = v;
    }
    if (tx == 0) {
#pragma unroll
        for (int i = 0; i < 8; ++i) {
            int r = r0 + i;
            if (r < M) out[r] = part[i] + b2v;
        }
    }
}

// ---------------- Aggregation + bias + BN + ReLU + residual ------------------
// One wave per node; float4 lanes (32 lanes = full 512B row); 2 half-waves on
// alternate edges, 4x unroll -> 8 gathers in flight. hwp rows pre-scaled by
// dis[src]; epilogue multiplies by dis[dst]. Combine via shfl_xor(,32).

__global__ __launch_bounds__(256) void agg_bn_kernel(
        const float* __restrict__ hwp, const int* __restrict__ row_ptr,
        const int* __restrict__ csr_src, const float* __restrict__ dis,
        const float* __restrict__ bc, const float* __restrict__ gamma_,
        const float* __restrict__ beta_, const float* __restrict__ rmean,
        const float* __restrict__ rvar,
        const float* __restrict__ h_in, float* __restrict__ h_out,
        int n, int residual) {
    int wid  = (blockIdx.x * 256 + threadIdx.x) >> 6;
    int lane = threadIdx.x & 63;
    if (wid >= n) return;
    const int half = lane >> 5;
    const int f    = (lane & 31) * 4;

    float4 a0 = {0.f, 0.f, 0.f, 0.f};
    float4 a1 = {0.f, 0.f, 0.f, 0.f};
    float4 a2 = {0.f, 0.f, 0.f, 0.f};
    float4 a3 = {0.f, 0.f, 0.f, 0.f};
    if (half == 0) a0 = *(const float4*)(hwp + (size_t)wid * H_C + f);

    const int beg = row_ptr[wid], end = row_ptr[wid + 1];
    int e = beg + half;
    for (; e + 6 < end; e += 8) {
        int s0 = csr_src[e];
        int s1 = csr_src[e + 2];
        int s2 = csr_src[e + 4];
        int s3 = csr_src[e + 6];
        float4 r0 = *(const float4*)(hwp + (size_t)s0 * H_C + f);
        float4 r1 = *(const float4*)(hwp + (size_t)s1 * H_C + f);
        float4 r2 = *(const float4*)(hwp + (size_t)s2 * H_C + f);
        float4 r3 = *(const float4*)(hwp + (size_t)s3 * H_C + f);
        add4(a0, r0);
        add4(a1, r1);
        add4(a2, r2);
        add4(a3, r3);
    }
    for (; e + 2 < end; e += 4) {
        int s0 = csr_src[e];
        int s1 = csr_src[e + 2];
        float4 r0 = *(const float4*)(hwp + (size_t)s0 * H_C + f);
        float4 r1 = *(const float4*)(hwp + (size_t)s1 * H_C + f);
        add4(a0, r0);
        add4(a1, r1);
    }
    if (e < end) {
        int s = csr_src[e];
        float4 r = *(const float4*)(hwp + (size_t)s * H_C + f);
        add4(a0, r);
    }
    add4(a0, a2);
    add4(a1, a3);
    add4(a0, a1);
    a0.x += __shfl_xor(a0.x, 32);
    a0.y += __shfl_xor(a0.y, 32);
    a0.z += __shfl_xor(a0.z, 32);
    a0.w += __shfl_xor(a0.w, 32);

    if (half == 0) {
        const float eps = 1e-5f;
        float dd = dis[wid];
        float4 b4 = *(const float4*)&bc[f];
        float4 g4 = *(const float4*)&gamma_[f];
        float4 be4 = *(const float4*)&beta_[f];
        float4 m4 = *(const float4*)&rmean[f];
        float4 v4 = *(const float4*)&rvar[f];
        float4 o;
        o.x = fmaf((fmaf(dd, a0.x, b4.x) - m4.x) * rsqrtf(v4.x + eps), g4.x, be4.x);
        o.y = fmaf((fmaf(dd, a0.y, b4.y) - m4.y) * rsqrtf(v4.y + eps), g4.y, be4.y);
        o.z = fmaf((fmaf(dd, a0.z, b4.z) - m4.z) * rsqrtf(v4.z + eps), g4.z, be4.z);
        o.w = fmaf((fmaf(dd, a0.w, b4.w) - m4.w) * rsqrtf(v4.w + eps), g4.w, be4.w);
        o.x = fmaxf(o.x, 0.f); o.y = fmaxf(o.y, 0.f);
        o.z = fmaxf(o.z, 0.f); o.w = fmaxf(o.w, 0.f);
        if (residual) {
            float4 r = *(const float4*)(h_in + (size_t)wid * H_C + f);
            add4(o, r);
        }
        *(float4*)(h_out + (size_t)wid * H_C + f) = o;
    }
}

// ---------------------------------------------------------------------------

extern "C" void kernel_launch(void* const* d_in, const int* in_sizes, int n_in,
                              void* d_out, int out_size, void* d_ws, size_t ws_size,
                              hipStream_t stream) {
    const float* x      = (const float*)d_in[0];
    const int*   ei     = (const int*)  d_in[1];
    const float* W_in   = (const float*)d_in[2];
    const float* b_in   = (const float*)d_in[3];
    const float* Wc     = (const float*)d_in[4];
    const float* bc     = (const float*)d_in[5];
    const float* gamma_ = (const float*)d_in[6];
    const float* beta_  = (const float*)d_in[7];
    const float* rmean  = (const float*)d_in[8];
    const float* rvar   = (const float*)d_in[9];
    const float* W1     = (const float*)d_in[10];
    const float* b1     = (const float*)d_in[11];
    const float* W2     = (const float*)d_in[12];
    const float* b2     = (const float*)d_in[13];
    float* out = (float*)d_out;

    const int M = in_sizes[0] / DIN_C;   // 50000 nodes
    const int E = in_sizes[1] / 2;       // 800000 edges
    const int* src = ei;
    const int* dst = ei + E;

    // Workspace carve-up (256B aligned)
    size_t off = 0;
    auto alloc = [&](size_t bytes) {
        void* p = (char*)d_ws + off;
        off += (bytes + 255) & ~(size_t)255;
        return p;
    };
    int*      cnt      = (int*)     alloc((size_t)M * 4);
    int*      excl     = (int*)     alloc((size_t)M * 4);
    int*      bsums    = (int*)     alloc(512);
    int*      btops    = (int*)     alloc(512);
    int*      row_ptr  = (int*)     alloc((size_t)(M + 1) * 4);
    int*      cursor   = (int*)     alloc((size_t)M * 4);
    float*    dis      = (float*)   alloc((size_t)M * 4);
    int*      csr_src  = (int*)     alloc((size_t)E * 4);
    ushort_t* lt_hi    = (ushort_t*)alloc((size_t)3 * 128 * 128 * 2);
    ushort_t* lt_lo    = (ushort_t*)alloc((size_t)3 * 128 * 128 * 2);
    ushort_t* it_hi    = (ushort_t*)alloc((size_t)128 * 64 * 2);
    ushort_t* it_lo    = (ushort_t*)alloc((size_t)128 * 64 * 2);
    float*    hA       = (float*)   alloc((size_t)M * H_C * 4);
    float*    hB       = (float*)   alloc((size_t)M * H_C * 4);
    float*    hw       = (float*)   alloc((size_t)M * H_C * 4);

    const int NB = (M + 511) / 512;

    // ---- W split+transpose (bf16 hi/lo) ----
    {
        const int total = 3 * 128 * 128 + 64 * 128;
        wsplit_kernel<<<(total + 255) / 256, 256, 0, stream>>>(
            Wc, W_in, lt_hi, lt_lo, it_hi, it_lo);
    }

    // ---- CSR build ----
    hipMemsetAsync(cnt, 0, (size_t)M * 4, stream);
    count_deg_kernel<<<(E + 255) / 256, 256, 0, stream>>>(dst, cnt, E);
    scan_blocks_kernel<<<NB, 512, 0, stream>>>(cnt, excl, bsums, M);
    scan_tops_kernel<<<1, 128, 0, stream>>>(bsums, btops, NB);
    finalize_nodes_kernel<<<NB, 512, 0, stream>>>(excl, btops, cnt, row_ptr, cursor, dis, M, E);
    fill_csr_kernel<<<(E + 255) / 256, 256, 0, stream>>>(src, dst, cursor, csr_src, E);

    const int GEMM_GRID = (M + 63) / 64;

    // ---- h0 = relu(x @ W_in + b_in)  [MFMA split, K=64] ----
    gemm_mfma_kernel<2, true, true, false><<<GEMM_GRID, 256, 0, stream>>>(
        x, it_hi, it_lo, b_in, nullptr, hA, M);

    // ---- 3 GCN layers ----
    float* cur = hA;
    float* nxt = hB;
    for (int layer = 0; layer < 3; ++layer) {
        // hw' = (h @ Wc) * dis[row]  [MFMA split, K=128]
        gemm_mfma_kernel<4, false, false, true><<<GEMM_GRID, 256, 0, stream>>>(
            cur, lt_hi + (size_t)layer * 16384, lt_lo + (size_t)layer * 16384,
            nullptr, dis, hw, M);
        agg_bn_kernel<<<(M * 64 + 255) / 256, 256, 0, stream>>>(
            hw, row_ptr, csr_src, dis,
            bc + (size_t)layer * H_C, gamma_ + (size_t)layer * H_C,
            beta_ + (size_t)layer * H_C, rmean + (size_t)layer * H_C,
            rvar + (size_t)layer * H_C,
            cur, nxt, M, layer > 0 ? 1 : 0);
        float* tmp = cur; cur = nxt; nxt = tmp;
    }

    // ---- fused head: out = relu(h @ W1 + b1) @ W2 + b2 ----
    {
        constexpr int RPB = (256 / (64 / 4)) * 8;  // 128 rows/block
        head_kernel<<<(M + RPB - 1) / RPB, 256, 0, stream>>>(
            cur, W1, b1, W2, b2, out, M);
    }
}